// Round 10
// baseline (669.651 us; speedup 1.0000x reference)
//
#include <hip/hip_runtime.h>

// HashEmbedding (Instant-NGP hash grid), MI355X gfx950.
// Round 10: spatial binning + LDS vertex staging.
// Key fact: x ~ U[0,1) => xn=(x+1)/2 in [0.5,1): points occupy 1/8 of the
// domain. Bin into 8192 cells of (1/32,1/32,1/64); per bin, levels 0..12
// have only ~27..600 distinct grid vertices -> stage them in LDS with
// ~2100 divergent gather lanes per bin instead of 8*cnt per level.
// Levels 13..15 stay direct. Divergent gather lanes/point: 128 -> ~42.

#define NLVL 16
#define TMASK ((1u << 19) - 1u)
#define P1 2654435761u
#define P2 805459861u

#define NBINS 8192          // 16 x 16 x 32 over the occupied half-cube
#define BINCAP 256          // mean 128, +11 sigma -> no overflow
#define NSTAGED 13          // levels 0..12 staged via LDS
#define MAXV 768            // max staged vertex count (l12: 10*10*6 = 600)

typedef unsigned short u16x8 __attribute__((ext_vector_type(8)));

__constant__ float c_res[NLVL] = {16.f, 20.f, 25.f, 32.f, 40.f, 50.f, 64.f, 80.f,
                                  101.f, 128.f, 161.f, 203.f, 256.f, 322.f, 406.f, 512.f};

__device__ __forceinline__ unsigned short f2bf(float f)
{
    unsigned u = __float_as_uint(f);
    u += 0x7FFFu + ((u >> 16) & 1u);        // round-to-nearest-even
    return (unsigned short)(u >> 16);
}

__device__ __forceinline__ void corner_idx(float xn0, float xn1, float xn2, float r,
                                           unsigned idx[8], float& w0, float& w1, float& w2)
{
    const float s0 = xn0 * r;
    const float s1 = xn1 * r;
    const float s2 = xn2 * r;
    const float f0 = floorf(s0);
    const float f1 = floorf(s1);
    const float f2 = floorf(s2);
    w0 = s0 - f0;
    w1 = s1 - f1;
    w2 = s2 - f2;
    const unsigned v0 = (unsigned)(int)f0;
    const unsigned v1 = (unsigned)(int)f1;
    const unsigned v2 = (unsigned)(int)f2;

    const unsigned ax0 = v0;
    const unsigned ax1 = v0 + 1u;
    const unsigned bx0 = v1 * P1;
    const unsigned bx1 = (v1 + 1u) * P1;
    const unsigned cx0 = v2 * P2;
    const unsigned cx1 = (v2 + 1u) * P2;

    idx[0] = (ax0 ^ bx0 ^ cx0) & TMASK;
    idx[1] = (ax0 ^ bx0 ^ cx1) & TMASK;
    idx[2] = (ax0 ^ bx1 ^ cx0) & TMASK;
    idx[3] = (ax0 ^ bx1 ^ cx1) & TMASK;
    idx[4] = (ax1 ^ bx0 ^ cx0) & TMASK;
    idx[5] = (ax1 ^ bx0 ^ cx1) & TMASK;
    idx[6] = (ax1 ^ bx1 ^ cx0) & TMASK;
    idx[7] = (ax1 ^ bx1 ^ cx1) & TMASK;
}

__device__ __forceinline__ float2 trilerp(const float2 e[8], float w0, float w1, float w2)
{
    const float omx = 1.0f - w0;
    const float omy = 1.0f - w1;
    const float omz = 1.0f - w2;

    const float c00x = e[0].x * omx + e[4].x * w0;
    const float c00y = e[0].y * omx + e[4].y * w0;
    const float c01x = e[1].x * omx + e[5].x * w0;
    const float c01y = e[1].y * omx + e[5].y * w0;
    const float c10x = e[2].x * omx + e[6].x * w0;
    const float c10y = e[2].y * omx + e[6].y * w0;
    const float c11x = e[3].x * omx + e[7].x * w0;
    const float c11y = e[3].y * omx + e[7].y * w0;

    const float c0x = c00x * omy + c10x * w1;
    const float c0y = c00y * omy + c10y * w1;
    const float c1x = c01x * omy + c11x * w1;
    const float c1y = c01y * omy + c11y * w1;

    float2 o;
    o.x = c0x * omz + c1x * w2;
    o.y = c0y * omz + c1y * w2;
    return o;
}

// ---- Kernel 1: scatter points into spatial bins ----
__global__ __launch_bounds__(256)
void k_scatter(const float* __restrict__ x,
               float4* __restrict__ bins,
               unsigned* __restrict__ counts)
{
    const int p = blockIdx.x * 256 + threadIdx.x;
    const float xn0 = (x[3 * p + 0] + 1.0f) * 0.5f;   // in [0.5, 1)
    const float xn1 = (x[3 * p + 1] + 1.0f) * 0.5f;
    const float xn2 = (x[3 * p + 2] + 1.0f) * 0.5f;
    const int bx = (int)((xn0 - 0.5f) * 32.f);        // 0..15
    const int by = (int)((xn1 - 0.5f) * 32.f);        // 0..15
    const int bz = (int)((xn2 - 0.5f) * 64.f);        // 0..31
    const int bin = ((bx << 4) + by) * 32 + bz;
    const unsigned slot = atomicAdd(&counts[bin], 1u);
    if (slot < BINCAP) {
        float4 e;
        e.x = xn0; e.y = xn1; e.z = xn2;
        e.w = __uint_as_float((unsigned)p);
        bins[(size_t)bin * BINCAP + slot] = e;
    }
}

// ---- Kernel 2: exclusive prefix sum of (clamped) counts -> bases ----
__global__ __launch_bounds__(1024)
void k_scan(const unsigned* __restrict__ counts, unsigned* __restrict__ bases)
{
    __shared__ unsigned s[1024];
    const int t = threadIdx.x;
    unsigned loc[8];
    unsigned sum = 0;
#pragma unroll
    for (int i = 0; i < 8; ++i) {
        loc[i] = sum;
        const unsigned c = counts[t * 8 + i];
        sum += (c < BINCAP ? c : BINCAP);
    }
    s[t] = sum;
    __syncthreads();
    for (int off = 1; off < 1024; off <<= 1) {
        const unsigned v = (t >= off) ? s[t - off] : 0u;
        __syncthreads();
        s[t] += v;
        __syncthreads();
    }
    const unsigned blockbase = (t > 0) ? s[t - 1] : 0u;
#pragma unroll
    for (int i = 0; i < 8; ++i)
        bases[t * 8 + i] = blockbase + loc[i];
}

// ---- Kernel 3: binned gather. One block per bin. ----
__global__ __launch_bounds__(256)
void k_gather_binned(const float4* __restrict__ bins,
                     const unsigned* __restrict__ counts,
                     const unsigned* __restrict__ bases,
                     const float* __restrict__ tables,
                     unsigned short* __restrict__ wsout,   // [n][32] bf16, sorted order
                     unsigned* __restrict__ rank)          // [n] sorted pos per point
{
    __shared__ float2 s_tab[MAXV];

    const int bin = blockIdx.x;
    const int bz = bin & 31;
    const int by = (bin >> 5) & 15;
    const int bx = bin >> 9;

    const unsigned craw = counts[bin];
    const unsigned cnt = (craw < BINCAP ? craw : BINCAP);
    const unsigned base = bases[bin];
    const int t = threadIdx.x;
    const bool act = (unsigned)t < cnt;

    float xn0 = 0.75f, xn1 = 0.75f, xn2 = 0.75f;
    unsigned pidx = 0;
    if (act) {
        const float4 e = bins[(size_t)bin * BINCAP + t];
        xn0 = e.x; xn1 = e.y; xn2 = e.z;
        pidx = __float_as_uint(e.w);
    }

    // bin bounds in xn-space (exact: (16+bx)/32 etc.)
    const float bxlo = 0.5f + bx * 0.03125f, bxhi = 0.5f + (bx + 1) * 0.03125f;
    const float bylo = 0.5f + by * 0.03125f, byhi = 0.5f + (by + 1) * 0.03125f;
    const float bzlo = 0.5f + bz * 0.015625f, bzhi = 0.5f + (bz + 1) * 0.015625f;

    float o[2 * NLVL];

    // ---- staged levels 0..NSTAGED-1 ----
#pragma unroll
    for (int l = 0; l < NSTAGED; ++l) {
        const float r = c_res[l];
        const int v0lo = (int)floorf(bxlo * r);
        const int v1lo = (int)floorf(bylo * r);
        const int v2lo = (int)floorf(bzlo * r);
        const int sx = (int)floorf(bxhi * r) + 2 - v0lo;   // covers RNE-up slack
        const int sy = (int)floorf(byhi * r) + 2 - v1lo;
        const int sz = (int)floorf(bzhi * r) + 2 - v2lo;
        const int syz = sy * sz;
        int V = sx * syz;
        if (V > MAXV) V = MAXV;   // provably not hit (l12 max = 600); memory safety

        const float2* __restrict__ tab = (const float2*)tables + ((size_t)l << 19);

        __syncthreads();   // previous level's consumers done
        {
            const int u0 = t, u1 = t + 256, u2 = t + 512;
            float2 r0, r1, r2;
            if (u0 < V) {
                const int i = u0 / syz, rem = u0 - i * syz, j = rem / sz, k = rem - j * sz;
                r0 = tab[((unsigned)(v0lo + i) ^ (unsigned)(v1lo + j) * P1 ^ (unsigned)(v2lo + k) * P2) & TMASK];
            }
            if (u1 < V) {
                const int i = u1 / syz, rem = u1 - i * syz, j = rem / sz, k = rem - j * sz;
                r1 = tab[((unsigned)(v0lo + i) ^ (unsigned)(v1lo + j) * P1 ^ (unsigned)(v2lo + k) * P2) & TMASK];
            }
            if (u2 < V) {
                const int i = u2 / syz, rem = u2 - i * syz, j = rem / sz, k = rem - j * sz;
                r2 = tab[((unsigned)(v0lo + i) ^ (unsigned)(v1lo + j) * P1 ^ (unsigned)(v2lo + k) * P2) & TMASK];
            }
            if (u0 < V) s_tab[u0] = r0;
            if (u1 < V) s_tab[u1] = r1;
            if (u2 < V) s_tab[u2] = r2;
        }
        __syncthreads();

        if (act) {
            const float s0 = xn0 * r, s1 = xn1 * r, s2 = xn2 * r;
            const float f0 = floorf(s0), f1 = floorf(s1), f2 = floorf(s2);
            const float w0 = s0 - f0, w1 = s1 - f1, w2 = s2 - f2;
            const int a = (int)f0 - v0lo, b = (int)f1 - v1lo, c = (int)f2 - v2lo;
            const int p000 = a * syz + b * sz + c;
            const float2 e000 = s_tab[p000];
            const float2 e001 = s_tab[p000 + 1];
            const float2 e010 = s_tab[p000 + sz];
            const float2 e011 = s_tab[p000 + sz + 1];
            const float2 e100 = s_tab[p000 + syz];
            const float2 e101 = s_tab[p000 + syz + 1];
            const float2 e110 = s_tab[p000 + syz + sz];
            const float2 e111 = s_tab[p000 + syz + sz + 1];
            const float omx = 1.f - w0, omy = 1.f - w1, omz = 1.f - w2;
            const float c00x = e000.x * omx + e100.x * w0;
            const float c00y = e000.y * omx + e100.y * w0;
            const float c01x = e001.x * omx + e101.x * w0;
            const float c01y = e001.y * omx + e101.y * w0;
            const float c10x = e010.x * omx + e110.x * w0;
            const float c10y = e010.y * omx + e110.y * w0;
            const float c11x = e011.x * omx + e111.x * w0;
            const float c11y = e011.y * omx + e111.y * w0;
            const float c0x = c00x * omy + c10x * w1;
            const float c0y = c00y * omy + c10y * w1;
            const float c1x = c01x * omy + c11x * w1;
            const float c1y = c01y * omy + c11y * w1;
            o[2 * l + 0] = c0x * omz + c1x * w2;
            o[2 * l + 1] = c0y * omz + c1y * w2;
        }
    }

    // ---- direct levels NSTAGED..15 : pair (13,14), then 15 ----
    if (act) {
        {
            const int lA = 13, lB = 14;
            const float2* tabA = (const float2*)tables + ((size_t)lA << 19);
            const float2* tabB = (const float2*)tables + ((size_t)lB << 19);
            unsigned ia[8], ib[8];
            float wa0, wa1, wa2, wb0, wb1, wb2;
            corner_idx(xn0, xn1, xn2, c_res[lA], ia, wa0, wa1, wa2);
            corner_idx(xn0, xn1, xn2, c_res[lB], ib, wb0, wb1, wb2);
            float2 ea[8], eb[8];
#pragma unroll
            for (int c = 0; c < 8; ++c) ea[c] = tabA[ia[c]];
#pragma unroll
            for (int c = 0; c < 8; ++c) eb[c] = tabB[ib[c]];
            const float2 oA = trilerp(ea, wa0, wa1, wa2);
            const float2 oB = trilerp(eb, wb0, wb1, wb2);
            o[2 * lA + 0] = oA.x; o[2 * lA + 1] = oA.y;
            o[2 * lB + 0] = oB.x; o[2 * lB + 1] = oB.y;
        }
        {
            const int lC = 15;
            const float2* tabC = (const float2*)tables + ((size_t)lC << 19);
            unsigned ic[8];
            float wc0, wc1, wc2;
            corner_idx(xn0, xn1, xn2, c_res[lC], ic, wc0, wc1, wc2);
            float2 ec[8];
#pragma unroll
            for (int c = 0; c < 8; ++c) ec[c] = tabC[ic[c]];
            const float2 oC = trilerp(ec, wc0, wc1, wc2);
            o[2 * lC + 0] = oC.x; o[2 * lC + 1] = oC.y;
        }

        const unsigned pos = base + (unsigned)t;
        u16x8* wp = (u16x8*)(wsout + (size_t)pos * 32);
#pragma unroll
        for (int q = 0; q < 4; ++q) {
            u16x8 v;
#pragma unroll
            for (int j = 0; j < 8; ++j) v[j] = f2bf(o[8 * q + j]);
            wp[q] = v;
        }
        rank[pidx] = pos;
    }
}

// ---- Kernel 4: un-permute + bf16->f32, coalesced out ----
__global__ __launch_bounds__(256)
void k_out(const unsigned short* __restrict__ wsout,
           const unsigned* __restrict__ rank,
           float4* __restrict__ out)
{
    const int p = blockIdx.x * 256 + threadIdx.x;
    const unsigned pos = rank[p];
    const u16x8* rp = (const u16x8*)(wsout + (size_t)pos * 32);
    u16x8 v0 = rp[0], v1 = rp[1], v2 = rp[2], v3 = rp[3];

    float4* op = out + (size_t)p * 8;
    float4 f;
#define CVT(h) __uint_as_float((unsigned)(h) << 16)
    f.x = CVT(v0[0]); f.y = CVT(v0[1]); f.z = CVT(v0[2]); f.w = CVT(v0[3]); op[0] = f;
    f.x = CVT(v0[4]); f.y = CVT(v0[5]); f.z = CVT(v0[6]); f.w = CVT(v0[7]); op[1] = f;
    f.x = CVT(v1[0]); f.y = CVT(v1[1]); f.z = CVT(v1[2]); f.w = CVT(v1[3]); op[2] = f;
    f.x = CVT(v1[4]); f.y = CVT(v1[5]); f.z = CVT(v1[6]); f.w = CVT(v1[7]); op[3] = f;
    f.x = CVT(v2[0]); f.y = CVT(v2[1]); f.z = CVT(v2[2]); f.w = CVT(v2[3]); op[4] = f;
    f.x = CVT(v2[4]); f.y = CVT(v2[5]); f.z = CVT(v2[6]); f.w = CVT(v2[7]); op[5] = f;
    f.x = CVT(v3[0]); f.y = CVT(v3[1]); f.z = CVT(v3[2]); f.w = CVT(v3[3]); op[6] = f;
    f.x = CVT(v3[4]); f.y = CVT(v3[5]); f.z = CVT(v3[6]); f.w = CVT(v3[7]); op[7] = f;
#undef CVT
}

// ---- Fallback: single-kernel f32 version (unexpected n or small ws) ----
__global__ __launch_bounds__(256)
void hash_embed_fallback(const float* __restrict__ x,
                         const float* __restrict__ tables,
                         float* __restrict__ out,
                         int n)
{
    const int p = blockIdx.x * 256 + threadIdx.x;
    if (p >= n) return;

    const float xn0 = (x[3 * p + 0] + 1.0f) * 0.5f;
    const float xn1 = (x[3 * p + 1] + 1.0f) * 0.5f;
    const float xn2 = (x[3 * p + 2] + 1.0f) * 0.5f;

    float o[2 * NLVL];
#pragma unroll
    for (int l = 0; l < NLVL; ++l) {
        const float2* tab = (const float2*)tables + ((size_t)l << 19);
        unsigned idx[8];
        float w0, w1, w2;
        corner_idx(xn0, xn1, xn2, c_res[l], idx, w0, w1, w2);
        float2 e[8];
#pragma unroll
        for (int c = 0; c < 8; ++c) e[c] = tab[idx[c]];
        const float2 v = trilerp(e, w0, w1, w2);
        o[2 * l + 0] = v.x;
        o[2 * l + 1] = v.y;
    }

    float4* op = (float4*)(out + (size_t)p * 32);
#pragma unroll
    for (int q = 0; q < 8; ++q)
        op[q] = make_float4(o[4 * q], o[4 * q + 1], o[4 * q + 2], o[4 * q + 3]);
}

extern "C" void kernel_launch(void* const* d_in, const int* in_sizes, int n_in,
                              void* d_out, int out_size, void* d_ws, size_t ws_size,
                              hipStream_t stream) {
    const float* x = (const float*)d_in[0];
    const float* tables = (const float*)d_in[1];
    float* out = (float*)d_out;
    const int n = in_sizes[0] / 3;                       // 1048576

    char* ws = (char*)d_ws;
    float4*         bins   = (float4*)(ws);                                  // 32 MB
    unsigned short* wsout  = (unsigned short*)(ws + ((size_t)32 << 20));     // 64 MB
    unsigned*       rank   = (unsigned*)(ws + ((size_t)96 << 20));           // 4 MB
    unsigned*       counts = (unsigned*)(ws + ((size_t)100 << 20));          // 32 KB
    unsigned*       bases  = (unsigned*)(ws + ((size_t)100 << 20) + 32768);  // 32 KB
    const size_t ws_needed = ((size_t)100 << 20) + 65536;

    if (n == (1 << 20) && ws_size >= ws_needed) {
        hipMemsetAsync(counts, 0, NBINS * sizeof(unsigned), stream);
        k_scatter<<<4096, 256, 0, stream>>>(x, bins, counts);
        k_scan<<<1, 1024, 0, stream>>>(counts, bases);
        k_gather_binned<<<NBINS, 256, 0, stream>>>(bins, counts, bases, tables, wsout, rank);
        k_out<<<4096, 256, 0, stream>>>(wsout, rank, (float4*)out);
    } else {
        hash_embed_fallback<<<(n + 255) / 256, 256, 0, stream>>>(x, tables, out, n);
    }
}

// Round 11
// 323.369 us; speedup vs baseline: 2.0709x; 2.0709x over previous
//
#include <hip/hip_runtime.h>

// HashEmbedding (Instant-NGP hash grid), MI355X gfx950.
// Round 11: spatial sort (two-pass scatter into 32^3 bins over the occupied
// [0.5,1)^3 half-cube) + the proven flat gather kernel run in sorted order
// with direct full-line output writes. Goal: cut distinct line-misses/point
// from 128 to ~50-65 (coarse/mid level corners become wave-shared + L1-hits).

#define NLVL 16
#define TMASK ((1u << 19) - 1u)
#define P1 2654435761u
#define P2 805459861u
#define NBINS 32768         // 32 x 32 x 32

__constant__ float c_res[NLVL] = {16.f, 20.f, 25.f, 32.f, 40.f, 50.f, 64.f, 80.f,
                                  101.f, 128.f, 161.f, 203.f, 256.f, 322.f, 406.f, 512.f};

__device__ __forceinline__ int bin_of(float xn0, float xn1, float xn2)
{
    int bx = (int)((xn0 - 0.5f) * 64.f);
    int by = (int)((xn1 - 0.5f) * 64.f);
    int bz = (int)((xn2 - 0.5f) * 64.f);
    bx = bx < 0 ? 0 : (bx > 31 ? 31 : bx);
    by = by < 0 ? 0 : (by > 31 ? 31 : by);
    bz = bz < 0 ? 0 : (bz > 31 ? 31 : bz);
    return (bx << 10) | (by << 5) | bz;
}

__device__ __forceinline__ void corner_idx(float xn0, float xn1, float xn2, float r,
                                           unsigned idx[8], float& w0, float& w1, float& w2)
{
    const float s0 = xn0 * r;
    const float s1 = xn1 * r;
    const float s2 = xn2 * r;
    const float f0 = floorf(s0);
    const float f1 = floorf(s1);
    const float f2 = floorf(s2);
    w0 = s0 - f0;
    w1 = s1 - f1;
    w2 = s2 - f2;
    const unsigned v0 = (unsigned)(int)f0;
    const unsigned v1 = (unsigned)(int)f1;
    const unsigned v2 = (unsigned)(int)f2;

    const unsigned ax0 = v0;
    const unsigned ax1 = v0 + 1u;
    const unsigned bx0 = v1 * P1;
    const unsigned bx1 = (v1 + 1u) * P1;
    const unsigned cx0 = v2 * P2;
    const unsigned cx1 = (v2 + 1u) * P2;

    idx[0] = (ax0 ^ bx0 ^ cx0) & TMASK;
    idx[1] = (ax0 ^ bx0 ^ cx1) & TMASK;
    idx[2] = (ax0 ^ bx1 ^ cx0) & TMASK;
    idx[3] = (ax0 ^ bx1 ^ cx1) & TMASK;
    idx[4] = (ax1 ^ bx0 ^ cx0) & TMASK;
    idx[5] = (ax1 ^ bx0 ^ cx1) & TMASK;
    idx[6] = (ax1 ^ bx1 ^ cx0) & TMASK;
    idx[7] = (ax1 ^ bx1 ^ cx1) & TMASK;
}

__device__ __forceinline__ float2 trilerp(const float2 e[8], float w0, float w1, float w2)
{
    const float omx = 1.0f - w0;
    const float omy = 1.0f - w1;
    const float omz = 1.0f - w2;

    const float c00x = e[0].x * omx + e[4].x * w0;
    const float c00y = e[0].y * omx + e[4].y * w0;
    const float c01x = e[1].x * omx + e[5].x * w0;
    const float c01y = e[1].y * omx + e[5].y * w0;
    const float c10x = e[2].x * omx + e[6].x * w0;
    const float c10y = e[2].y * omx + e[6].y * w0;
    const float c11x = e[3].x * omx + e[7].x * w0;
    const float c11y = e[3].y * omx + e[7].y * w0;

    const float c0x = c00x * omy + c10x * w1;
    const float c0y = c00y * omy + c10y * w1;
    const float c1x = c01x * omy + c11x * w1;
    const float c1y = c01y * omy + c11y * w1;

    float2 o;
    o.x = c0x * omz + c1x * w2;
    o.y = c0y * omz + c1y * w2;
    return o;
}

// ---- Pass 1: count points per bin ----
__global__ __launch_bounds__(256)
void k_count(const float* __restrict__ x, unsigned* __restrict__ counts)
{
    const int p = blockIdx.x * 256 + threadIdx.x;
    const float xn0 = (x[3 * p + 0] + 1.0f) * 0.5f;
    const float xn1 = (x[3 * p + 1] + 1.0f) * 0.5f;
    const float xn2 = (x[3 * p + 2] + 1.0f) * 0.5f;
    atomicAdd(&counts[bin_of(xn0, xn1, xn2)], 1u);
}

// ---- Pass 2: exclusive scan of counts -> cursor (mutable bases) ----
__global__ __launch_bounds__(1024)
void k_scan(const unsigned* __restrict__ counts, unsigned* __restrict__ cursor)
{
    __shared__ unsigned s[1024];
    const int t = threadIdx.x;
    unsigned loc[32];
    unsigned sum = 0;
#pragma unroll
    for (int i = 0; i < 32; ++i) {
        loc[i] = sum;
        sum += counts[t * 32 + i];
    }
    s[t] = sum;
    __syncthreads();
    for (int off = 1; off < 1024; off <<= 1) {
        const unsigned v = (t >= off) ? s[t - off] : 0u;
        __syncthreads();
        s[t] += v;
        __syncthreads();
    }
    const unsigned blockbase = (t > 0) ? s[t - 1] : 0u;
#pragma unroll
    for (int i = 0; i < 32; ++i)
        cursor[t * 32 + i] = blockbase + loc[i];
}

// ---- Pass 3: place points in bin-sorted order ----
__global__ __launch_bounds__(256)
void k_place(const float* __restrict__ x,
             unsigned* __restrict__ cursor,
             float4* __restrict__ sorted_pts)
{
    const int p = blockIdx.x * 256 + threadIdx.x;
    const float xn0 = (x[3 * p + 0] + 1.0f) * 0.5f;
    const float xn1 = (x[3 * p + 1] + 1.0f) * 0.5f;
    const float xn2 = (x[3 * p + 2] + 1.0f) * 0.5f;
    const unsigned pos = atomicAdd(&cursor[bin_of(xn0, xn1, xn2)], 1u);
    float4 e;
    e.x = xn0; e.y = xn1; e.z = xn2; e.w = __uint_as_float((unsigned)p);
    sorted_pts[pos] = e;
}

// ---- Pass 4: gather in sorted order, write out[pidx] directly ----
__global__ __launch_bounds__(256)
void k_gather_sorted(const float4* __restrict__ sorted_pts,
                     const float* __restrict__ tables,
                     float* __restrict__ out)
{
    const int sp = blockIdx.x * 256 + threadIdx.x;
    const float4 e = sorted_pts[sp];
    const float xn0 = e.x, xn1 = e.y, xn2 = e.z;
    const unsigned pidx = __float_as_uint(e.w);

    float o[2 * NLVL];
#pragma unroll
    for (int l = 0; l < NLVL; ++l) {
        const float2* __restrict__ tab = (const float2*)tables + ((size_t)l << 19);
        unsigned idx[8];
        float w0, w1, w2;
        corner_idx(xn0, xn1, xn2, c_res[l], idx, w0, w1, w2);
        float2 ee[8];
#pragma unroll
        for (int c = 0; c < 8; ++c) ee[c] = tab[idx[c]];
        const float2 v = trilerp(ee, w0, w1, w2);
        o[2 * l + 0] = v.x;
        o[2 * l + 1] = v.y;
    }

    float4* op = (float4*)(out + (size_t)pidx * 32);
#pragma unroll
    for (int q = 0; q < 8; ++q)
        op[q] = make_float4(o[4 * q], o[4 * q + 1], o[4 * q + 2], o[4 * q + 3]);
}

// ---- Fallback: single-kernel f32 version (unexpected n or small ws) ----
__global__ __launch_bounds__(256)
void hash_embed_fallback(const float* __restrict__ x,
                         const float* __restrict__ tables,
                         float* __restrict__ out,
                         int n)
{
    const int p = blockIdx.x * 256 + threadIdx.x;
    if (p >= n) return;

    const float xn0 = (x[3 * p + 0] + 1.0f) * 0.5f;
    const float xn1 = (x[3 * p + 1] + 1.0f) * 0.5f;
    const float xn2 = (x[3 * p + 2] + 1.0f) * 0.5f;

    float o[2 * NLVL];
#pragma unroll
    for (int l = 0; l < NLVL; ++l) {
        const float2* tab = (const float2*)tables + ((size_t)l << 19);
        unsigned idx[8];
        float w0, w1, w2;
        corner_idx(xn0, xn1, xn2, c_res[l], idx, w0, w1, w2);
        float2 ee[8];
#pragma unroll
        for (int c = 0; c < 8; ++c) ee[c] = tab[idx[c]];
        const float2 v = trilerp(ee, w0, w1, w2);
        o[2 * l + 0] = v.x;
        o[2 * l + 1] = v.y;
    }

    float4* op = (float4*)(out + (size_t)p * 32);
#pragma unroll
    for (int q = 0; q < 8; ++q)
        op[q] = make_float4(o[4 * q], o[4 * q + 1], o[4 * q + 2], o[4 * q + 3]);
}

extern "C" void kernel_launch(void* const* d_in, const int* in_sizes, int n_in,
                              void* d_out, int out_size, void* d_ws, size_t ws_size,
                              hipStream_t stream) {
    const float* x = (const float*)d_in[0];
    const float* tables = (const float*)d_in[1];
    float* out = (float*)d_out;
    const int n = in_sizes[0] / 3;                       // 1048576

    char* ws = (char*)d_ws;
    float4*   sorted_pts = (float4*)ws;                                   // 16 MB
    unsigned* counts     = (unsigned*)(ws + ((size_t)16 << 20));          // 128 KB
    unsigned* cursor     = (unsigned*)(ws + ((size_t)16 << 20) + (128 << 10)); // 128 KB
    const size_t ws_needed = ((size_t)16 << 20) + (256 << 10);

    if (n == (1 << 20) && ws_size >= ws_needed) {
        hipMemsetAsync(counts, 0, NBINS * sizeof(unsigned), stream);
        k_count<<<4096, 256, 0, stream>>>(x, counts);
        k_scan<<<1, 1024, 0, stream>>>(counts, cursor);
        k_place<<<4096, 256, 0, stream>>>(x, cursor, sorted_pts);
        k_gather_sorted<<<4096, 256, 0, stream>>>(sorted_pts, tables, out);
    } else {
        hash_embed_fallback<<<(n + 255) / 256, 256, 0, stream>>>(x, tables, out, n);
    }
}

// Round 12
// 321.215 us; speedup vs baseline: 2.0847x; 1.0067x over previous
//
#include <hip/hip_runtime.h>

// HashEmbedding (Instant-NGP hash grid), MI355X gfx950.
// Round 12: R11 (spatial counting sort + sorted flat gather) + XCD-chunk
// swizzle on the gather: XCD q gets a contiguous 1/8 of the sorted points,
// so its L2 holds the tables' lines for one spatial slab instead of
// competing with 7 other XCDs across the whole domain.

#define NLVL 16
#define TMASK ((1u << 19) - 1u)
#define P1 2654435761u
#define P2 805459861u
#define NBINS 32768         // 32 x 32 x 32

__constant__ float c_res[NLVL] = {16.f, 20.f, 25.f, 32.f, 40.f, 50.f, 64.f, 80.f,
                                  101.f, 128.f, 161.f, 203.f, 256.f, 322.f, 406.f, 512.f};

__device__ __forceinline__ int bin_of(float xn0, float xn1, float xn2)
{
    int bx = (int)((xn0 - 0.5f) * 64.f);
    int by = (int)((xn1 - 0.5f) * 64.f);
    int bz = (int)((xn2 - 0.5f) * 64.f);
    bx = bx < 0 ? 0 : (bx > 31 ? 31 : bx);
    by = by < 0 ? 0 : (by > 31 ? 31 : by);
    bz = bz < 0 ? 0 : (bz > 31 ? 31 : bz);
    return (bx << 10) | (by << 5) | bz;
}

__device__ __forceinline__ void corner_idx(float xn0, float xn1, float xn2, float r,
                                           unsigned idx[8], float& w0, float& w1, float& w2)
{
    const float s0 = xn0 * r;
    const float s1 = xn1 * r;
    const float s2 = xn2 * r;
    const float f0 = floorf(s0);
    const float f1 = floorf(s1);
    const float f2 = floorf(s2);
    w0 = s0 - f0;
    w1 = s1 - f1;
    w2 = s2 - f2;
    const unsigned v0 = (unsigned)(int)f0;
    const unsigned v1 = (unsigned)(int)f1;
    const unsigned v2 = (unsigned)(int)f2;

    const unsigned ax0 = v0;
    const unsigned ax1 = v0 + 1u;
    const unsigned bx0 = v1 * P1;
    const unsigned bx1 = (v1 + 1u) * P1;
    const unsigned cx0 = v2 * P2;
    const unsigned cx1 = (v2 + 1u) * P2;

    idx[0] = (ax0 ^ bx0 ^ cx0) & TMASK;
    idx[1] = (ax0 ^ bx0 ^ cx1) & TMASK;
    idx[2] = (ax0 ^ bx1 ^ cx0) & TMASK;
    idx[3] = (ax0 ^ bx1 ^ cx1) & TMASK;
    idx[4] = (ax1 ^ bx0 ^ cx0) & TMASK;
    idx[5] = (ax1 ^ bx0 ^ cx1) & TMASK;
    idx[6] = (ax1 ^ bx1 ^ cx0) & TMASK;
    idx[7] = (ax1 ^ bx1 ^ cx1) & TMASK;
}

__device__ __forceinline__ float2 trilerp(const float2 e[8], float w0, float w1, float w2)
{
    const float omx = 1.0f - w0;
    const float omy = 1.0f - w1;
    const float omz = 1.0f - w2;

    const float c00x = e[0].x * omx + e[4].x * w0;
    const float c00y = e[0].y * omx + e[4].y * w0;
    const float c01x = e[1].x * omx + e[5].x * w0;
    const float c01y = e[1].y * omx + e[5].y * w0;
    const float c10x = e[2].x * omx + e[6].x * w0;
    const float c10y = e[2].y * omx + e[6].y * w0;
    const float c11x = e[3].x * omx + e[7].x * w0;
    const float c11y = e[3].y * omx + e[7].y * w0;

    const float c0x = c00x * omy + c10x * w1;
    const float c0y = c00y * omy + c10y * w1;
    const float c1x = c01x * omy + c11x * w1;
    const float c1y = c01y * omy + c11y * w1;

    float2 o;
    o.x = c0x * omz + c1x * w2;
    o.y = c0y * omz + c1y * w2;
    return o;
}

// ---- Pass 1: count points per bin ----
__global__ __launch_bounds__(256)
void k_count(const float* __restrict__ x, unsigned* __restrict__ counts)
{
    const int p = blockIdx.x * 256 + threadIdx.x;
    const float xn0 = (x[3 * p + 0] + 1.0f) * 0.5f;
    const float xn1 = (x[3 * p + 1] + 1.0f) * 0.5f;
    const float xn2 = (x[3 * p + 2] + 1.0f) * 0.5f;
    atomicAdd(&counts[bin_of(xn0, xn1, xn2)], 1u);
}

// ---- Pass 2: exclusive scan of counts -> cursor (mutable bases) ----
__global__ __launch_bounds__(1024)
void k_scan(const unsigned* __restrict__ counts, unsigned* __restrict__ cursor)
{
    __shared__ unsigned s[1024];
    const int t = threadIdx.x;
    unsigned loc[32];
    unsigned sum = 0;
#pragma unroll
    for (int i = 0; i < 32; ++i) {
        loc[i] = sum;
        sum += counts[t * 32 + i];
    }
    s[t] = sum;
    __syncthreads();
    for (int off = 1; off < 1024; off <<= 1) {
        const unsigned v = (t >= off) ? s[t - off] : 0u;
        __syncthreads();
        s[t] += v;
        __syncthreads();
    }
    const unsigned blockbase = (t > 0) ? s[t - 1] : 0u;
#pragma unroll
    for (int i = 0; i < 32; ++i)
        cursor[t * 32 + i] = blockbase + loc[i];
}

// ---- Pass 3: place points in bin-sorted order ----
__global__ __launch_bounds__(256)
void k_place(const float* __restrict__ x,
             unsigned* __restrict__ cursor,
             float4* __restrict__ sorted_pts)
{
    const int p = blockIdx.x * 256 + threadIdx.x;
    const float xn0 = (x[3 * p + 0] + 1.0f) * 0.5f;
    const float xn1 = (x[3 * p + 1] + 1.0f) * 0.5f;
    const float xn2 = (x[3 * p + 2] + 1.0f) * 0.5f;
    const unsigned pos = atomicAdd(&cursor[bin_of(xn0, xn1, xn2)], 1u);
    float4 e;
    e.x = xn0; e.y = xn1; e.z = xn2; e.w = __uint_as_float((unsigned)p);
    sorted_pts[pos] = e;
}

// ---- Pass 4: gather in sorted order (XCD-chunked), write out[pidx] ----
__global__ __launch_bounds__(256)
void k_gather_sorted(const float4* __restrict__ sorted_pts,
                     const float* __restrict__ tables,
                     float* __restrict__ out)
{
    // XCD-chunk swizzle: round-robin dispatch sends bid&7 -> XCD; remap so
    // XCD q processes the contiguous sorted chunk [q*512, (q+1)*512) blocks.
    const unsigned bid = blockIdx.x;
    const unsigned newbid = (bid & 7u) * 512u + (bid >> 3);
    const int sp = (int)(newbid * 256u + threadIdx.x);

    const float4 e = sorted_pts[sp];
    const float xn0 = e.x, xn1 = e.y, xn2 = e.z;
    const unsigned pidx = __float_as_uint(e.w);

    float o[2 * NLVL];
#pragma unroll
    for (int l = 0; l < NLVL; ++l) {
        const float2* __restrict__ tab = (const float2*)tables + ((size_t)l << 19);
        unsigned idx[8];
        float w0, w1, w2;
        corner_idx(xn0, xn1, xn2, c_res[l], idx, w0, w1, w2);
        float2 ee[8];
#pragma unroll
        for (int c = 0; c < 8; ++c) ee[c] = tab[idx[c]];
        const float2 v = trilerp(ee, w0, w1, w2);
        o[2 * l + 0] = v.x;
        o[2 * l + 1] = v.y;
    }

    float4* op = (float4*)(out + (size_t)pidx * 32);
#pragma unroll
    for (int q = 0; q < 8; ++q)
        op[q] = make_float4(o[4 * q], o[4 * q + 1], o[4 * q + 2], o[4 * q + 3]);
}

// ---- Fallback: single-kernel f32 version (unexpected n or small ws) ----
__global__ __launch_bounds__(256)
void hash_embed_fallback(const float* __restrict__ x,
                         const float* __restrict__ tables,
                         float* __restrict__ out,
                         int n)
{
    const int p = blockIdx.x * 256 + threadIdx.x;
    if (p >= n) return;

    const float xn0 = (x[3 * p + 0] + 1.0f) * 0.5f;
    const float xn1 = (x[3 * p + 1] + 1.0f) * 0.5f;
    const float xn2 = (x[3 * p + 2] + 1.0f) * 0.5f;

    float o[2 * NLVL];
#pragma unroll
    for (int l = 0; l < NLVL; ++l) {
        const float2* tab = (const float2*)tables + ((size_t)l << 19);
        unsigned idx[8];
        float w0, w1, w2;
        corner_idx(xn0, xn1, xn2, c_res[l], idx, w0, w1, w2);
        float2 ee[8];
#pragma unroll
        for (int c = 0; c < 8; ++c) ee[c] = tab[idx[c]];
        const float2 v = trilerp(ee, w0, w1, w2);
        o[2 * l + 0] = v.x;
        o[2 * l + 1] = v.y;
    }

    float4* op = (float4*)(out + (size_t)p * 32);
#pragma unroll
    for (int q = 0; q < 8; ++q)
        op[q] = make_float4(o[4 * q], o[4 * q + 1], o[4 * q + 2], o[4 * q + 3]);
}

extern "C" void kernel_launch(void* const* d_in, const int* in_sizes, int n_in,
                              void* d_out, int out_size, void* d_ws, size_t ws_size,
                              hipStream_t stream) {
    const float* x = (const float*)d_in[0];
    const float* tables = (const float*)d_in[1];
    float* out = (float*)d_out;
    const int n = in_sizes[0] / 3;                       // 1048576

    char* ws = (char*)d_ws;
    float4*   sorted_pts = (float4*)ws;                                   // 16 MB
    unsigned* counts     = (unsigned*)(ws + ((size_t)16 << 20));          // 128 KB
    unsigned* cursor     = (unsigned*)(ws + ((size_t)16 << 20) + (128 << 10)); // 128 KB
    const size_t ws_needed = ((size_t)16 << 20) + (256 << 10);

    if (n == (1 << 20) && ws_size >= ws_needed) {
        hipMemsetAsync(counts, 0, NBINS * sizeof(unsigned), stream);
        k_count<<<4096, 256, 0, stream>>>(x, counts);
        k_scan<<<1, 1024, 0, stream>>>(counts, cursor);
        k_place<<<4096, 256, 0, stream>>>(x, cursor, sorted_pts);
        k_gather_sorted<<<4096, 256, 0, stream>>>(sorted_pts, tables, out);
    } else {
        hash_embed_fallback<<<(n + 255) / 256, 256, 0, stream>>>(x, tables, out, n);
    }
}